// Round 13
// baseline (1486.203 us; speedup 1.0000x reference)
//
#include <hip/hip_runtime.h>
#include <hip/hip_bf16.h>
#include <stdint.h>

typedef __attribute__((ext_vector_type(8))) short short8_t;   // 8 x bf16 (4 VGPRs)
typedef __attribute__((ext_vector_type(4))) float f32x4;      // MFMA accum / nt vec

__device__ __forceinline__ unsigned short f2bf(float f) {
  union { float f; unsigned int u; } a;
  a.f = f;
  unsigned int u = a.u;
  u += 0x7fffu + ((u >> 16) & 1u);   // round-to-nearest-even
  return (unsigned short)(u >> 16);
}

__device__ __forceinline__ void gload_lds16(const void* g, void* l) {
  __builtin_amdgcn_global_load_lds(
      (const __attribute__((address_space(1))) void*)g,
      (__attribute__((address_space(3))) void*)l, 16, 0, 0);
}

// ---------------- LayerNorm: fp32 -> bf16 normed rows ----------------
constexpr int D_IN = 4096;

__global__ __launch_bounds__(256) void ln_bf16_kernel(
    const float* __restrict__ x, const float* __restrict__ lnw,
    const float* __restrict__ lnb, unsigned short* __restrict__ out) {
  const int row = blockIdx.x;
  const int tid = threadIdx.x;
  const float* xr = x + (size_t)row * D_IN;

  f32x4 v[4];
  float sum = 0.f, sq = 0.f;
#pragma unroll
  for (int i = 0; i < 4; ++i) {
    v[i] = __builtin_nontemporal_load(
        reinterpret_cast<const f32x4*>(xr + i * 1024 + tid * 4));
    sum += v[i][0] + v[i][1] + v[i][2] + v[i][3];
    sq += v[i][0]*v[i][0] + v[i][1]*v[i][1] + v[i][2]*v[i][2] + v[i][3]*v[i][3];
  }
#pragma unroll
  for (int off = 32; off > 0; off >>= 1) {
    sum += __shfl_down(sum, off, 64);
    sq  += __shfl_down(sq, off, 64);
  }
  __shared__ float s_sum[4], s_sq[4];
  if ((tid & 63) == 0) { s_sum[tid >> 6] = sum; s_sq[tid >> 6] = sq; }
  __syncthreads();
  const float fs = s_sum[0] + s_sum[1] + s_sum[2] + s_sum[3];
  const float fq = s_sq[0] + s_sq[1] + s_sq[2] + s_sq[3];
  const float mean = fs * (1.f / D_IN);
  const float var = fq * (1.f / D_IN) - mean * mean;
  const float rstd = rsqrtf(var + 1e-5f);

  unsigned short* orow = out + (size_t)row * D_IN;
#pragma unroll
  for (int i = 0; i < 4; ++i) {
    const int col = i * 1024 + tid * 4;
    const f32x4 w = *reinterpret_cast<const f32x4*>(lnw + col);
    const f32x4 b = *reinterpret_cast<const f32x4*>(lnb + col);
    ushort4 o;
    o.x = f2bf((v[i][0] - mean) * rstd * w[0] + b[0]);
    o.y = f2bf((v[i][1] - mean) * rstd * w[1] + b[1]);
    o.z = f2bf((v[i][2] - mean) * rstd * w[2] + b[2]);
    o.w = f2bf((v[i][3] - mean) * rstd * w[3] + b[3]);
    *reinterpret_cast<ushort4*>(orow + col) = o;
  }
}

// ---------------- Weight cast fp32 -> bf16 ----------------
__global__ __launch_bounds__(256) void f32_to_bf16_kernel(
    const float* __restrict__ in, unsigned short* __restrict__ out) {
  const size_t i = ((size_t)blockIdx.x * 256 + threadIdx.x) * 8;
  const f32x4 a = __builtin_nontemporal_load(reinterpret_cast<const f32x4*>(in + i));
  const f32x4 b = __builtin_nontemporal_load(reinterpret_cast<const f32x4*>(in + i + 4));
  ushort4 lo, hi;
  lo.x = f2bf(a[0]); lo.y = f2bf(a[1]); lo.z = f2bf(a[2]); lo.w = f2bf(a[3]);
  hi.x = f2bf(b[0]); hi.y = f2bf(b[1]); hi.z = f2bf(b[2]); hi.w = f2bf(b[3]);
  *reinterpret_cast<ushort4*>(out + i) = lo;
  *reinterpret_cast<ushort4*>(out + i + 4) = hi;
}

// ---------------- 256x256 bf16 GEMM: 16 waves (4Mx4N), X/Y regions ------
// C = A(MxK) * B(NxK)^T + bias.  1024 threads = 16 waves, per-wave 64x64 out.
// BK=64, 2-slot dbuf: A slot0/1 @ 0/32K, B slot0/1 @ 64K/96K (128 KiB).
// Swizzle byte ^= ((row&7)<<4): r6-verified 0 conflicts (same per-wave read
// shape).  Read addr = laneBase[kk] + imm only.
// CHANGE vs r12 (single variable): 8 -> 16 waves. r12 ledger: MFMA 54% +
// LDS-service 33-50% SUM to the measured time (2 waves/SIMD can't overlap
// the two pipes).  4 waves/SIMD interleave read-bursts with MFMA-bursts.
// acc 64 + frags 32 + addr ~15 VGPR: fits 128-cap for 4 waves/SIMD.
// Stage unit = 128 rows (1024 thr x 16B = 16KB); 4 loads/ktile; vmcnt(4).

#define RDA(S, KK, ROW) \
  (*reinterpret_cast<const short8_t*>(((KK) ? aB1 : aB0) + (S)*32768 + (ROW)*128))
#define RDB(S, KK, ROW) \
  (*reinterpret_cast<const short8_t*>(((KK) ? bB1 : bB0) + (S)*32768 + (ROW)*128))

#define READ_A2(S, MH)                                         \
  _Pragma("unroll") for (int m_ = 0; m_ < 2; ++m_) {           \
    af[(MH)*2+m_][0] = RDA(S, 0, ((MH)*2+m_)*16);              \
    af[(MH)*2+m_][1] = RDA(S, 1, ((MH)*2+m_)*16);              \
  }

#define READ_B2(S, NH)                                         \
  _Pragma("unroll") for (int n_ = 0; n_ < 2; ++n_) {           \
    bfr[(NH)*2+n_][0] = RDB(S, 0, ((NH)*2+n_)*16);             \
    bfr[(NH)*2+n_][1] = RDB(S, 1, ((NH)*2+n_)*16);             \
  }

#define MFMA_Q(MH, NH)                                                         \
  _Pragma("unroll") for (int kk_ = 0; kk_ < 2; ++kk_) {                        \
    _Pragma("unroll") for (int m_ = 0; m_ < 2; ++m_) {                         \
      _Pragma("unroll") for (int n_ = 0; n_ < 2; ++n_)                         \
        acc[(MH)*2+m_][(NH)*2+n_] = __builtin_amdgcn_mfma_f32_16x16x32_bf16(   \
            af[(MH)*2+m_][kk_], bfr[(NH)*2+n_][kk_], acc[(MH)*2+m_][(NH)*2+n_], 0, 0, 0); \
    }                                                                          \
  }

#define STAGE_A(S, U, KT) \
  gload_lds16(aSrc + (size_t)((U)*128) * K + (size_t)(KT)*64, ldsAw + (S)*32768 + (U)*16384)
#define STAGE_B(S, U, KT) \
  gload_lds16(bSrc + (size_t)((U)*128) * K + (size_t)(KT)*64, ldsBw + (S)*32768 + (U)*16384)
#define STAGE_ALL(S, KT)                                       \
  STAGE_A(S,0,KT); STAGE_A(S,1,KT); STAGE_B(S,0,KT); STAGE_B(S,1,KT);

// X region: all 16 slot reads + 2 MFMA quadrants; stage-WAR gate (lgkm drain)
#define XREG(S)                                                \
  READ_A2(S, 0) READ_B2(S, 0)                                  \
  __builtin_amdgcn_s_setprio(1);                               \
  MFMA_Q(0,0)                                                  \
  READ_B2(S, 1)                                                \
  MFMA_Q(0,1)                                                  \
  READ_A2(S, 1)                                                \
  __builtin_amdgcn_s_setprio(0);                               \
  asm volatile("s_waitcnt lgkmcnt(0)" ::: "memory");           \
  __builtin_amdgcn_s_barrier();                                \
  asm volatile("" ::: "memory");

// Y region: stage refill (4 units) + 2 MFMA quadrants; counted-vmcnt gate
#define YREG(S, KT)                                            \
  STAGE_ALL(S, KT)                                             \
  __builtin_amdgcn_s_setprio(1);                               \
  MFMA_Q(1,0)                                                  \
  MFMA_Q(1,1)                                                  \
  __builtin_amdgcn_s_setprio(0);                               \
  asm volatile("s_waitcnt vmcnt(4)" ::: "memory");             \
  __builtin_amdgcn_s_barrier();                                \
  asm volatile("" ::: "memory");

__global__ __launch_bounds__(1024, 4) void gemm_xy16(
    const unsigned short* __restrict__ A,   // M x K bf16
    const unsigned short* __restrict__ B,   // N x K bf16
    const float* __restrict__ bias,         // N fp32
    float* __restrict__ C,                  // M x N fp32
    int M, int N, int K, int NYB, int BXP) {
  extern __shared__ char smem[];
  const int tid = threadIdx.x;
  const int lane = tid & 63;
  const int wid = tid >> 6;                 // 0..15
  const int wr = wid >> 2, wc = wid & 3;    // 4M x 4N waves
  const int fr = lane & 15;
  const int q16 = (lane >> 4) * 16;

  // Super-tiled XCD mapping (r12): window per XCD = 8(by) x BXP(bx)
  const int id = blockIdx.x;
  const int xcd = id & 7;
  const int s = id >> 3;
  const int gsz = 8 * BXP;
  const int g = s / gsz;
  const int j = s - g * gsz;
  const int by = g * 8 + (j & 7);
  const int bx = xcd * BXP + (j >> 3);
  const int m0 = by * 256, n0 = bx * 256;

  // inverse-swizzled global source for linear global_load_lds dest
  const int s_log = (tid * 16) ^ (((tid >> 3) & 7) << 4);
  const int rsw = s_log >> 7;               // 0..127 (128-row stage unit)
  const int csw = (s_log & 127) >> 1;
  const unsigned short* aSrc = A + (size_t)(m0 + rsw) * K + csw;
  const unsigned short* bSrc = B + (size_t)(n0 + rsw) * K + csw;

  char* const ldsAw = smem + wid * 1024;           // wave-uniform stage bases
  char* const ldsBw = smem + 65536 + wid * 1024;

  // lane-base pointers: fragment reads are base + compile-time offset
  const int s7 = (fr & 7) << 4;
  const char* const aB0 = smem + (wr * 64 + fr) * 128 + (q16 ^ s7);
  const char* const aB1 = smem + (wr * 64 + fr) * 128 + ((64 + q16) ^ s7);
  const char* const bB0 = smem + 65536 + (wc * 64 + fr) * 128 + (q16 ^ s7);
  const char* const bB1 = smem + 65536 + (wc * 64 + fr) * 128 + ((64 + q16) ^ s7);

  f32x4 acc[4][4] = {};
  short8_t af[4][2], bfr[4][2];

  // ---- prologue: ktile0 -> slot0, ktile1 -> slot1 (4 units each) ----
  STAGE_ALL(0, 0)
  STAGE_ALL(1, 1)
  asm volatile("s_waitcnt vmcnt(4)" ::: "memory");   // ktile0 landed
  __builtin_amdgcn_s_barrier();
  asm volatile("" ::: "memory");

  const int NK = K >> 6;   // BK=64 ktiles (even, >= 4)
  for (int t = 0; t < (NK - 2) >> 1; ++t) {
    const int k2 = 2*t + 2, k3 = 2*t + 3;
    XREG(0) YREG(0, k2)      // ktile 2t   (slot0), refill slot0 <- 2t+2
    XREG(1) YREG(1, k3)      // ktile 2t+1 (slot1), refill slot1 <- 2t+3
  }
  // ---- tail: ktiles NK-2 (slot0), NK-1 (slot1); no more staging ----
  {
    READ_A2(0, 0) READ_B2(0, 0)
    __builtin_amdgcn_s_setprio(1);
    MFMA_Q(0,0)
    READ_B2(0, 1)
    MFMA_Q(0,1)
    READ_A2(0, 1)
    MFMA_Q(1,0)
    MFMA_Q(1,1)
    __builtin_amdgcn_s_setprio(0);
    asm volatile("s_waitcnt lgkmcnt(0)\n\ts_waitcnt vmcnt(0)" ::: "memory");
    __builtin_amdgcn_s_barrier();    // ktile NK-1 landed & published
    asm volatile("" ::: "memory");
    READ_A2(1, 0) READ_B2(1, 0)
    __builtin_amdgcn_s_setprio(1);
    MFMA_Q(0,0)
    READ_B2(1, 1)
    MFMA_Q(0,1)
    READ_A2(1, 1)
    MFMA_Q(1,0)
    MFMA_Q(1,1)
    __builtin_amdgcn_s_setprio(0);
  }

  // ---- epilogue: 4 x 64-row half-tiles through one LDS buffer, nt stores --
  __syncthreads();   // all waves' K-loop LDS reads done before overwrite
  float* const buf = (float*)smem;   // 64 x 260 fp32 (66,560 B)
  const int cr = (lane >> 4) * 4;
  float bv[4];
#pragma unroll
  for (int ni = 0; ni < 4; ++ni) bv[ni] = bias[n0 + wc * 64 + ni * 16 + fr];

#pragma unroll
  for (int half = 0; half < 4; ++half) {
    if (wr == half) {   // 4 waves (wc 0..3) fill the 64x256 half-tile
#pragma unroll
      for (int mi = 0; mi < 4; ++mi) {
#pragma unroll
        for (int jj = 0; jj < 4; ++jj) {
          const int lr = mi * 16 + cr + jj;   // 0..63
#pragma unroll
          for (int ni = 0; ni < 4; ++ni)
            buf[lr * 260 + wc * 64 + ni * 16 + fr] = acc[mi][ni][jj] + bv[ni];
        }
      }
    }
    __syncthreads();
    // store: wave w handles rows w*4 .. w*4+3 (1KB contiguous per row)
#pragma unroll
    for (int i = 0; i < 4; ++i) {
      const int idx = wid * 4 + i;   // 0..63
      const f32x4 vv = *reinterpret_cast<const f32x4*>(buf + idx * 260 + lane * 4);
      const int grow = m0 + half * 64 + idx;
      __builtin_nontemporal_store(
          vv, reinterpret_cast<f32x4*>(C + (size_t)grow * N + n0) + lane);
    }
    __syncthreads();
  }
}

extern "C" void kernel_launch(void* const* d_in, const int* in_sizes, int n_in,
                              void* d_out, int out_size, void* d_ws, size_t ws_size,
                              hipStream_t stream) {
  const float* x    = (const float*)d_in[0];
  const float* w    = (const float*)d_in[1];
  const float* bias = (const float*)d_in[2];
  const float* lnw  = (const float*)d_in[3];
  const float* lnb  = (const float*)d_in[4];
  float* out = (float*)d_out;

  const int DIN  = 4096;
  const int M    = in_sizes[0] / DIN;      // 8192
  const int DOUT = in_sizes[2];            // 12288

  unsigned short* normA = (unsigned short*)d_ws;                 // M x DIN bf16
  unsigned short* wB    = normA + (size_t)M * DIN;               // DOUT x DIN bf16

  ln_bf16_kernel<<<M, 256, 0, stream>>>(x, lnw, lnb, normA);
  f32_to_bf16_kernel<<<((size_t)DOUT * DIN) / (256 * 8), 256, 0, stream>>>(w, wB);

  const int nwg = (M / 256) * (DOUT / 256);   // 1536
  (void)hipFuncSetAttribute((const void*)gemm_xy16,
                            hipFuncAttributeMaxDynamicSharedMemorySize, 131072);
  gemm_xy16<<<nwg, 1024, 131072, stream>>>(normA, wB, bias, out,
                                           M, DOUT, DIN, M / 256, (DOUT / 256) / 8);
}

// Round 14
// 757.112 us; speedup vs baseline: 1.9630x; 1.9630x over previous
//
#include <hip/hip_runtime.h>
#include <hip/hip_bf16.h>
#include <stdint.h>

typedef __attribute__((ext_vector_type(8))) short short8_t;   // 8 x bf16 (4 VGPRs)
typedef __attribute__((ext_vector_type(4))) float f32x4;      // MFMA accum / nt vec

__device__ __forceinline__ unsigned short f2bf(float f) {
  union { float f; unsigned int u; } a;
  a.f = f;
  unsigned int u = a.u;
  u += 0x7fffu + ((u >> 16) & 1u);   // round-to-nearest-even
  return (unsigned short)(u >> 16);
}

__device__ __forceinline__ void gload_lds16(const void* g, void* l) {
  __builtin_amdgcn_global_load_lds(
      (const __attribute__((address_space(1))) void*)g,
      (__attribute__((address_space(3))) void*)l, 16, 0, 0);
}

// ---------------- LayerNorm: fp32 -> bf16 normed rows ----------------
constexpr int D_IN = 4096;

__global__ __launch_bounds__(256) void ln_bf16_kernel(
    const float* __restrict__ x, const float* __restrict__ lnw,
    const float* __restrict__ lnb, unsigned short* __restrict__ out) {
  const int row = blockIdx.x;
  const int tid = threadIdx.x;
  const float* xr = x + (size_t)row * D_IN;

  f32x4 v[4];
  float sum = 0.f, sq = 0.f;
#pragma unroll
  for (int i = 0; i < 4; ++i) {
    v[i] = __builtin_nontemporal_load(
        reinterpret_cast<const f32x4*>(xr + i * 1024 + tid * 4));
    sum += v[i][0] + v[i][1] + v[i][2] + v[i][3];
    sq += v[i][0]*v[i][0] + v[i][1]*v[i][1] + v[i][2]*v[i][2] + v[i][3]*v[i][3];
  }
#pragma unroll
  for (int off = 32; off > 0; off >>= 1) {
    sum += __shfl_down(sum, off, 64);
    sq  += __shfl_down(sq, off, 64);
  }
  __shared__ float s_sum[4], s_sq[4];
  if ((tid & 63) == 0) { s_sum[tid >> 6] = sum; s_sq[tid >> 6] = sq; }
  __syncthreads();
  const float fs = s_sum[0] + s_sum[1] + s_sum[2] + s_sum[3];
  const float fq = s_sq[0] + s_sq[1] + s_sq[2] + s_sq[3];
  const float mean = fs * (1.f / D_IN);
  const float var = fq * (1.f / D_IN) - mean * mean;
  const float rstd = rsqrtf(var + 1e-5f);

  unsigned short* orow = out + (size_t)row * D_IN;
#pragma unroll
  for (int i = 0; i < 4; ++i) {
    const int col = i * 1024 + tid * 4;
    const f32x4 w = *reinterpret_cast<const f32x4*>(lnw + col);
    const f32x4 b = *reinterpret_cast<const f32x4*>(lnb + col);
    ushort4 o;
    o.x = f2bf((v[i][0] - mean) * rstd * w[0] + b[0]);
    o.y = f2bf((v[i][1] - mean) * rstd * w[1] + b[1]);
    o.z = f2bf((v[i][2] - mean) * rstd * w[2] + b[2]);
    o.w = f2bf((v[i][3] - mean) * rstd * w[3] + b[3]);
    *reinterpret_cast<ushort4*>(orow + col) = o;
  }
}

// ---------------- Weight cast fp32 -> bf16 ----------------
__global__ __launch_bounds__(256) void f32_to_bf16_kernel(
    const float* __restrict__ in, unsigned short* __restrict__ out) {
  const size_t i = ((size_t)blockIdx.x * 256 + threadIdx.x) * 8;
  const f32x4 a = __builtin_nontemporal_load(reinterpret_cast<const f32x4*>(in + i));
  const f32x4 b = __builtin_nontemporal_load(reinterpret_cast<const f32x4*>(in + i + 4));
  ushort4 lo, hi;
  lo.x = f2bf(a[0]); lo.y = f2bf(a[1]); lo.z = f2bf(a[2]); lo.w = f2bf(a[3]);
  hi.x = f2bf(b[0]); hi.y = f2bf(b[1]); hi.z = f2bf(b[2]); hi.w = f2bf(b[3]);
  *reinterpret_cast<ushort4*>(out + i) = lo;
  *reinterpret_cast<ushort4*>(out + i + 4) = hi;
}

// ---------------- 256x256 bf16 GEMM: 16 waves (4Mx4N), kk-rotating frags ----
// C = A(MxK) * B(NxK)^T + bias.  1024 threads = 16 waves, per-wave 64x64 out.
// BK=64, 2-slot dbuf: A slot0/1 @ 0/32K, B slot0/1 @ 64K/96K (128 KiB).
// Swizzle byte ^= ((row&7)<<4): 0 conflicts (r6/r13-verified pattern).
// r13 FAILED on register spill (arch cap 64 with acc 64 in AGPR; demand ~85
// -> scratch traffic 3.5 GB).  FIX (single concept): kk-rotation — hold only
// ONE kk-pass of fragments (af[4]+bfr[4] = 32 VGPR): read kk0 (8) -> 16 MFMA
// -> read kk1 into SAME regs (in-order WAR) -> 16 MFMA in Y.  Demand ~52.
// Schedule/stage ledger/mapping/epilogue = r13 unchanged.

#define RD(P, IMM) (*reinterpret_cast<const short8_t*>((P) + (IMM)))

#define READ8(S, KK)                                                \
  _Pragma("unroll") for (int m_ = 0; m_ < 4; ++m_)                  \
    af[m_] = RD((KK) ? aB1 : aB0, (S)*32768 + m_*2048);             \
  _Pragma("unroll") for (int n_ = 0; n_ < 4; ++n_)                  \
    bfr[n_] = RD((KK) ? bB1 : bB0, (S)*32768 + n_*2048);

#define MFMA16                                                      \
  _Pragma("unroll") for (int m_ = 0; m_ < 4; ++m_) {                \
    _Pragma("unroll") for (int n_ = 0; n_ < 4; ++n_)                \
      acc[m_][n_] = __builtin_amdgcn_mfma_f32_16x16x32_bf16(        \
          af[m_], bfr[n_], acc[m_][n_], 0, 0, 0);                   \
  }

#define STAGE_A(S, U, KT) \
  gload_lds16(aSrc + (size_t)((U)*128) * K + (size_t)(KT)*64, ldsAw + (S)*32768 + (U)*16384)
#define STAGE_B(S, U, KT) \
  gload_lds16(bSrc + (size_t)((U)*128) * K + (size_t)(KT)*64, ldsBw + (S)*32768 + (U)*16384)
#define STAGE_ALL(S, KT)                                            \
  STAGE_A(S,0,KT); STAGE_A(S,1,KT); STAGE_B(S,0,KT); STAGE_B(S,1,KT);

// X region: kk0 reads + 16 MFMA + kk1 reads; stage-WAR gate (lgkm drain)
#define XREG(S)                                                     \
  READ8(S, 0)                                                       \
  __builtin_amdgcn_s_setprio(1);                                    \
  MFMA16                                                            \
  READ8(S, 1)                                                       \
  __builtin_amdgcn_s_setprio(0);                                    \
  asm volatile("s_waitcnt lgkmcnt(0)" ::: "memory");                \
  __builtin_amdgcn_s_barrier();                                     \
  asm volatile("" ::: "memory");

// Y region: stage refill (4 units) + kk1's 16 MFMA; counted-vmcnt gate
#define YREG(S, KT)                                                 \
  STAGE_ALL(S, KT)                                                  \
  __builtin_amdgcn_s_setprio(1);                                    \
  MFMA16                                                            \
  __builtin_amdgcn_s_setprio(0);                                    \
  asm volatile("s_waitcnt vmcnt(4)" ::: "memory");                  \
  __builtin_amdgcn_s_barrier();                                     \
  asm volatile("" ::: "memory");

__global__ __launch_bounds__(1024, 4) void gemm_xy16(
    const unsigned short* __restrict__ A,   // M x K bf16
    const unsigned short* __restrict__ B,   // N x K bf16
    const float* __restrict__ bias,         // N fp32
    float* __restrict__ C,                  // M x N fp32
    int M, int N, int K, int NYB, int BXP) {
  extern __shared__ char smem[];
  const int tid = threadIdx.x;
  const int lane = tid & 63;
  const int wid = tid >> 6;                 // 0..15
  const int wr = wid >> 2, wc = wid & 3;    // 4M x 4N waves
  const int fr = lane & 15;
  const int q16 = (lane >> 4) * 16;

  // Super-tiled XCD mapping (r12): window per XCD = 8(by) x BXP(bx)
  const int id = blockIdx.x;
  const int xcd = id & 7;
  const int s = id >> 3;
  const int gsz = 8 * BXP;
  const int g = s / gsz;
  const int j = s - g * gsz;
  const int by = g * 8 + (j & 7);
  const int bx = xcd * BXP + (j >> 3);
  const int m0 = by * 256, n0 = bx * 256;

  // inverse-swizzled global source for linear global_load_lds dest
  const int s_log = (tid * 16) ^ (((tid >> 3) & 7) << 4);
  const int rsw = s_log >> 7;               // 0..127 (128-row stage unit)
  const int csw = (s_log & 127) >> 1;
  const unsigned short* aSrc = A + (size_t)(m0 + rsw) * K + csw;
  const unsigned short* bSrc = B + (size_t)(n0 + rsw) * K + csw;

  char* const ldsAw = smem + wid * 1024;           // wave-uniform stage bases
  char* const ldsBw = smem + 65536 + wid * 1024;

  // lane-base pointers per kk: fragment reads = base + compile-time offset
  const int s7 = (fr & 7) << 4;
  const char* const aB0 = smem + (wr * 64 + fr) * 128 + (q16 ^ s7);
  const char* const aB1 = smem + (wr * 64 + fr) * 128 + ((64 + q16) ^ s7);
  const char* const bB0 = smem + 65536 + (wc * 64 + fr) * 128 + (q16 ^ s7);
  const char* const bB1 = smem + 65536 + (wc * 64 + fr) * 128 + ((64 + q16) ^ s7);

  f32x4 acc[4][4] = {};       // 64 regs -> AGPR
  short8_t af[4], bfr[4];     // 32 VGPR, kk-rotated

  // ---- prologue: ktile0 -> slot0, ktile1 -> slot1 (4 units each) ----
  STAGE_ALL(0, 0)
  STAGE_ALL(1, 1)
  asm volatile("s_waitcnt vmcnt(4)" ::: "memory");   // ktile0 landed
  __builtin_amdgcn_s_barrier();
  asm volatile("" ::: "memory");

  const int NK = K >> 6;   // BK=64 ktiles (even, >= 4)
  for (int t = 0; t < (NK - 2) >> 1; ++t) {
    const int k2 = 2*t + 2, k3 = 2*t + 3;
    XREG(0) YREG(0, k2)      // ktile 2t   (slot0), refill slot0 <- 2t+2
    XREG(1) YREG(1, k3)      // ktile 2t+1 (slot1), refill slot1 <- 2t+3
  }
  // ---- tail: ktiles NK-2 (slot0), NK-1 (slot1); no more staging ----
  {
    READ8(0, 0)
    __builtin_amdgcn_s_setprio(1);
    MFMA16
    READ8(0, 1)
    MFMA16
    __builtin_amdgcn_s_setprio(0);
    asm volatile("s_waitcnt lgkmcnt(0)\n\ts_waitcnt vmcnt(0)" ::: "memory");
    __builtin_amdgcn_s_barrier();    // ktile NK-1 landed & published
    asm volatile("" ::: "memory");
    READ8(1, 0)
    __builtin_amdgcn_s_setprio(1);
    MFMA16
    READ8(1, 1)
    MFMA16
    __builtin_amdgcn_s_setprio(0);
  }

  // ---- epilogue: 4 x 64-row half-tiles through one LDS buffer, nt stores --
  __syncthreads();   // all waves' K-loop LDS reads done before overwrite
  float* const buf = (float*)smem;   // 64 x 260 fp32 (66,560 B)
  const int cr = (lane >> 4) * 4;
  float bv[4];
#pragma unroll
  for (int ni = 0; ni < 4; ++ni) bv[ni] = bias[n0 + wc * 64 + ni * 16 + fr];

#pragma unroll
  for (int half = 0; half < 4; ++half) {
    if (wr == half) {   // 4 waves (wc 0..3) fill the 64x256 half-tile
#pragma unroll
      for (int mi = 0; mi < 4; ++mi) {
#pragma unroll
        for (int jj = 0; jj < 4; ++jj) {
          const int lr = mi * 16 + cr + jj;   // 0..63
#pragma unroll
          for (int ni = 0; ni < 4; ++ni)
            buf[lr * 260 + wc * 64 + ni * 16 + fr] = acc[mi][ni][jj] + bv[ni];
        }
      }
    }
    __syncthreads();
    // store: wave w handles rows w*4 .. w*4+3 (1KB contiguous per row)
#pragma unroll
    for (int i = 0; i < 4; ++i) {
      const int idx = wid * 4 + i;   // 0..63
      const f32x4 vv = *reinterpret_cast<const f32x4*>(buf + idx * 260 + lane * 4);
      const int grow = m0 + half * 64 + idx;
      __builtin_nontemporal_store(
          vv, reinterpret_cast<f32x4*>(C + (size_t)grow * N + n0) + lane);
    }
    __syncthreads();
  }
}

extern "C" void kernel_launch(void* const* d_in, const int* in_sizes, int n_in,
                              void* d_out, int out_size, void* d_ws, size_t ws_size,
                              hipStream_t stream) {
  const float* x    = (const float*)d_in[0];
  const float* w    = (const float*)d_in[1];
  const float* bias = (const float*)d_in[2];
  const float* lnw  = (const float*)d_in[3];
  const float* lnb  = (const float*)d_in[4];
  float* out = (float*)d_out;

  const int DIN  = 4096;
  const int M    = in_sizes[0] / DIN;      // 8192
  const int DOUT = in_sizes[2];            // 12288

  unsigned short* normA = (unsigned short*)d_ws;                 // M x DIN bf16
  unsigned short* wB    = normA + (size_t)M * DIN;               // DOUT x DIN bf16

  ln_bf16_kernel<<<M, 256, 0, stream>>>(x, lnw, lnb, normA);
  f32_to_bf16_kernel<<<((size_t)DOUT * DIN) / (256 * 8), 256, 0, stream>>>(w, wB);

  const int nwg = (M / 256) * (DOUT / 256);   // 1536
  (void)hipFuncSetAttribute((const void*)gemm_xy16,
                            hipFuncAttributeMaxDynamicSharedMemorySize, 131072);
  gemm_xy16<<<nwg, 1024, 131072, stream>>>(normA, wB, bias, out,
                                           M, DOUT, DIN, M / 256, (DOUT / 256) / 8);
}